// Round 1
// baseline (1950.888 us; speedup 1.0000x reference)
//
#include <hip/hip_runtime.h>
#include <stdint.h>

// ---- problem constants ----
#define NPATCH 3136      // 64 images * 49 patches
#define MPAD   3200      // padded to 25 * 128
#define NBANK  100000
#define DIM    768
#define BM 128
#define BN 128
#define BK 64
#define KTILES (DIM / BK)   // 12
#define MT 25               // MPAD / BM
#define NT 782              // ceil(NBANK / BN)

typedef __attribute__((ext_vector_type(4))) float f32x4;
typedef __attribute__((ext_vector_type(4))) unsigned int u32x4;
typedef __attribute__((ext_vector_type(8))) __bf16 bf16x8;

// monotonic float<->uint mapping for atomicMax on floats (incl. negatives)
__device__ __forceinline__ unsigned fkey(float f) {
    unsigned u = __float_as_uint(f);
    return (u & 0x80000000u) ? ~u : (u | 0x80000000u);
}
__device__ __forceinline__ float funkey(unsigned u) {
    return __uint_as_float((u & 0x80000000u) ? (u ^ 0x80000000u) : ~u);
}

// fp32 -> bf16 RNE, bit-level (self-contained, matches hardware cvt)
__device__ __forceinline__ unsigned short f2bf(float x) {
    unsigned u = __float_as_uint(x);
    u += 0x7FFFu + ((u >> 16) & 1u);
    return (unsigned short)(u >> 16);
}

// ---- kernel 0: zero the per-patch max-key buffer ----
__global__ void k_init(unsigned* __restrict__ keys) {
    int i = blockIdx.x * 256 + threadIdx.x;
    if (i < MPAD) keys[i] = 0u;   // decodes to <any real key>; replaced by first real max
}

// ---- kernel 1: normalize patches (drop CLS) -> bf16 A[MPAD][DIM]; zero pad rows ----
__global__ void k_patches(const float* __restrict__ tokens, unsigned short* __restrict__ A) {
    int wv = threadIdx.x >> 6, lane = threadIdx.x & 63;
    int r = blockIdx.x * 4 + wv;
    if (r >= MPAD) return;
    unsigned short* dst = A + (size_t)r * DIM;
    if (r >= NPATCH) {
        for (int i = lane; i < DIM / 4; i += 64)
            ((ushort4*)dst)[i] = make_ushort4(0, 0, 0, 0);
        return;
    }
    int b = r / 49, j = r % 49;
    const float* src = tokens + (size_t)(b * 50 + 1 + j) * DIM;  // skip CLS token
    f32x4 v[3];
    float ss = 0.f;
#pragma unroll
    for (int i = 0; i < 3; i++) {
        v[i] = ((const f32x4*)src)[lane + 64 * i];
        ss += v[i][0]*v[i][0] + v[i][1]*v[i][1] + v[i][2]*v[i][2] + v[i][3]*v[i][3];
    }
#pragma unroll
    for (int d = 1; d < 64; d <<= 1) ss += __shfl_xor(ss, d);
    float sc = 1.0f / (sqrtf(ss) + 1e-12f);
#pragma unroll
    for (int i = 0; i < 3; i++) {
        ushort4 o;
        o.x = f2bf(v[i][0] * sc); o.y = f2bf(v[i][1] * sc);
        o.z = f2bf(v[i][2] * sc); o.w = f2bf(v[i][3] * sc);
        ((ushort4*)dst)[lane + 64 * i] = o;
    }
}

// ---- kernel 2: per-row 1/(||mb||+eps) ----
__global__ void k_rs(const float* __restrict__ mb, float* __restrict__ rs) {
    int wv = threadIdx.x >> 6, lane = threadIdx.x & 63;
    int r = blockIdx.x * 4 + wv;
    if (r >= NBANK) return;
    const f32x4* src = (const f32x4*)(mb + (size_t)r * DIM);
    float ss = 0.f;
#pragma unroll
    for (int i = 0; i < 3; i++) {
        f32x4 v = src[lane + 64 * i];
        ss += v[0]*v[0] + v[1]*v[1] + v[2]*v[2] + v[3]*v[3];
    }
#pragma unroll
    for (int d = 1; d < 64; d <<= 1) ss += __shfl_xor(ss, d);
    if (lane == 0) rs[r] = 1.0f / (sqrtf(ss) + 1e-12f);
}

// ---- kernel 3: bf16 MFMA GEMM (A=patches bf16, B=bank fp32 normalized on the fly),
//      fused row-max -> atomicMax(keys) ----
__global__ void __launch_bounds__(256) k_gemm(const unsigned short* __restrict__ A,
                                              const float* __restrict__ mb,
                                              const float* __restrict__ rs,
                                              unsigned* __restrict__ keys) {
    __shared__ unsigned short Al[2][BM * BK];   // [row][k] bf16, 16 KB each
    __shared__ unsigned short Bl[2][BN * BK];   // [n][k]  bf16, 16 KB each

    const int bid = blockIdx.x;
    const int mt = bid % MT;          // m-fastest: 25 consecutive blocks share one B tile (L2 reuse)
    const int nt = bid / MT;
    const int t = threadIdx.x;
    const int lane = t & 63, wv = t >> 6;

    // B staging geometry: 2048 16B-chunks per (BN x BK fp32) tile, 8 per thread.
    // Each thread's 8 rows are fixed across K-tiles -> load rs once.
    int brow[8];
    float rsv[8];
#pragma unroll
    for (int it = 0; it < 8; it++) {
        int id = it * 256 + t;
        int row = id >> 4;
        int gr = nt * BN + row;
        brow[it] = (gr < NBANK) ? gr : (NBANK - 1);  // clamp tail (masked in epilogue)
        rsv[it] = rs[brow[it]];
    }

    const unsigned short* Ab = A + (size_t)(mt * BM) * DIM;

    f32x4 breg[8];

    auto stageA = [&](int buf, int kt) {            // async global->LDS, 16B/lane
#pragma unroll
        for (int it = 0; it < 4; it++) {
            int id = it * 256 + t;
            int row = id >> 3, cc = id & 7;
            const unsigned short* g = Ab + (size_t)row * DIM + kt * BK + cc * 8;
            unsigned short* l = &Al[buf][id * 8];   // linear: uniform base + lane*16
            __builtin_amdgcn_global_load_lds(
                (const __attribute__((address_space(1))) unsigned int*)g,
                (__attribute__((address_space(3))) unsigned int*)l, 16, 0, 0);
        }
    };
    auto loadB = [&](int kt) {                      // issue fp32 loads into regs
#pragma unroll
        for (int it = 0; it < 8; it++) {
            int id = it * 256 + t;
            int c4 = id & 15;
            breg[it] = *(const f32x4*)(mb + (size_t)brow[it] * DIM + kt * BK + c4 * 4);
        }
    };
    auto writeB = [&](int buf) {                    // normalize, cvt bf16, LDS write
#pragma unroll
        for (int it = 0; it < 8; it++) {
            int id = it * 256 + t;
            int row = id >> 4, c4 = id & 15;
            f32x4 v = breg[it] * rsv[it];
            ushort4 o;
            o.x = f2bf(v[0]); o.y = f2bf(v[1]); o.z = f2bf(v[2]); o.w = f2bf(v[3]);
            *(ushort4*)(&Bl[buf][row * BK + c4 * 4]) = o;
        }
    };

    // wave -> 64x64 output quadrant; 4x4 fragments of 16x16x32
    f32x4 acc[4][4] = {};
    const int wm = (wv >> 1) * 64;
    const int wn = (wv & 1) * 64;
    const int lr = lane & 15;          // A-row / B-col within fragment
    const int lk = (lane >> 4) * 8;    // k offset within fragment

    auto compute = [&](int buf) {
#pragma unroll
        for (int ks = 0; ks < BK; ks += 32) {
            bf16x8 av[4], bv[4];
#pragma unroll
            for (int mi = 0; mi < 4; mi++)
                av[mi] = __builtin_bit_cast(bf16x8,
                    *(const u32x4*)(&Al[buf][(wm + mi * 16 + lr) * BK + ks + lk]));
#pragma unroll
            for (int ni = 0; ni < 4; ni++)
                bv[ni] = __builtin_bit_cast(bf16x8,
                    *(const u32x4*)(&Bl[buf][(wn + ni * 16 + lr) * BK + ks + lk]));
#pragma unroll
            for (int mi = 0; mi < 4; mi++)
#pragma unroll
                for (int ni = 0; ni < 4; ni++)
                    acc[mi][ni] = __builtin_amdgcn_mfma_f32_16x16x32_bf16(
                        av[mi], bv[ni], acc[mi][ni], 0, 0, 0);
        }
    };

    // 2-phase pipeline: one barrier per K-tile; stage(next) issued before compute(cur)
    stageA(0, 0);
    loadB(0);
    int cur = 0;
    for (int kt = 0; kt < KTILES; kt++) {
        writeB(cur);
        __syncthreads();               // cur fully staged (vmcnt drain covers stageA)
        if (kt + 1 < KTILES) { stageA(cur ^ 1, kt + 1); loadB(kt + 1); }
        compute(cur);
        cur ^= 1;
    }

    // epilogue: row-max over this block's 128 columns, then global atomicMax
    const int rowbase = mt * BM + wm;
    const int colbase = nt * BN + wn;
#pragma unroll
    for (int mi = 0; mi < 4; mi++) {
#pragma unroll
        for (int j = 0; j < 4; j++) {
            float m = -3.4e38f;
#pragma unroll
            for (int ni = 0; ni < 4; ni++) {
                int col = colbase + ni * 16 + lr;
                if (col < NBANK) m = fmaxf(m, acc[mi][ni][j]);
            }
#pragma unroll
            for (int d = 1; d < 16; d <<= 1)   // reduce 16 lanes sharing a C-row
                m = fmaxf(m, __shfl_xor(m, d));
            if (lr == 0) {
                int row = rowbase + mi * 16 + (lane >> 4) * 4 + j;
                if (row < NPATCH) atomicMax(&keys[row], fkey(m));
            }
        }
    }
}

// ---- kernel 4: scores[b] = max_j sqrt(max(2 - 2*c_max, 1e-12)) ----
__global__ void k_final(const unsigned* __restrict__ keys, float* __restrict__ out) {
    int b = threadIdx.x;
    if (b >= 64) return;
    float best = 0.f;
    for (int j = 0; j < 49; j++) {
        float c = funkey(keys[b * 49 + j]);
        float d2 = fmaxf(2.0f - 2.0f * c, 1e-12f);
        best = fmaxf(best, sqrtf(d2));
    }
    out[b] = best;
}

extern "C" void kernel_launch(void* const* d_in, const int* in_sizes, int n_in,
                              void* d_out, int out_size, void* d_ws, size_t ws_size,
                              hipStream_t stream) {
    const float* tokens = (const float*)d_in[0];   // [64, 50, 768] f32
    const float* mb     = (const float*)d_in[1];   // [100000, 768] f32
    float* out = (float*)d_out;                    // [64] f32

    // ws layout: A bf16 [3200*768] | rs f32 [100000] | keys u32 [3200]  (~5.33 MB)
    char* ws = (char*)d_ws;
    unsigned short* A = (unsigned short*)ws;
    float* rs         = (float*)(ws + (size_t)MPAD * DIM * 2);
    unsigned* keys    = (unsigned*)(ws + (size_t)MPAD * DIM * 2 + (size_t)NBANK * 4);

    k_init   <<<(MPAD + 255) / 256, 256, 0, stream>>>(keys);
    k_patches<<<MPAD / 4, 256, 0, stream>>>(tokens, A);
    k_rs     <<<(NBANK + 3) / 4, 256, 0, stream>>>(mb, rs);
    k_gemm   <<<MT * NT, 256, 0, stream>>>(A, mb, rs, keys);
    k_final  <<<1, 64, 0, stream>>>(keys, out);
}

// Round 2
// 918.157 us; speedup vs baseline: 2.1248x; 2.1248x over previous
//
#include <hip/hip_runtime.h>
#include <stdint.h>

// ---- problem constants ----
#define NPATCH 3136      // 64 images * 49 patches
#define MPAD   3200      // padded to 25 * 128
#define NBANK  100000
#define NBPAD  100096    // 782 * 128
#define DIM    768
#define BM 128
#define BN 128
#define BK 64
#define KTILES (DIM / BK)   // 12
#define MT 25               // MPAD / BM
#define NT 782              // NBPAD / BN

typedef __attribute__((ext_vector_type(4))) float f32x4;
typedef __attribute__((ext_vector_type(4))) unsigned int u32x4;
typedef __attribute__((ext_vector_type(8))) __bf16 bf16x8;

// monotonic float<->uint mapping for atomicMax on floats (incl. negatives)
__device__ __forceinline__ unsigned fkey(float f) {
    unsigned u = __float_as_uint(f);
    return (u & 0x80000000u) ? ~u : (u | 0x80000000u);
}
__device__ __forceinline__ float funkey(unsigned u) {
    return __uint_as_float((u & 0x80000000u) ? (u ^ 0x80000000u) : ~u);
}

// fp32 -> bf16 RNE, bit-level
__device__ __forceinline__ unsigned short f2bf(float x) {
    unsigned u = __float_as_uint(x);
    u += 0x7FFFu + ((u >> 16) & 1u);
    return (unsigned short)(u >> 16);
}

// ---- kernel 0: zero the per-patch max-key buffer ----
__global__ void k_init(unsigned* __restrict__ keys) {
    int i = blockIdx.x * 256 + threadIdx.x;
    if (i < MPAD) keys[i] = 0u;
}

// ---- kernel 1: normalize patches (drop CLS) -> bf16 A[MPAD][DIM]; zero pad rows ----
__global__ void k_patches(const float* __restrict__ tokens, unsigned short* __restrict__ A) {
    int wv = threadIdx.x >> 6, lane = threadIdx.x & 63;
    int r = blockIdx.x * 4 + wv;
    if (r >= MPAD) return;
    unsigned short* dst = A + (size_t)r * DIM;
    if (r >= NPATCH) {
        for (int i = lane; i < DIM / 4; i += 64)
            ((ushort4*)dst)[i] = make_ushort4(0, 0, 0, 0);
        return;
    }
    int b = r / 49, j = r % 49;
    const float* src = tokens + (size_t)(b * 50 + 1 + j) * DIM;  // skip CLS
    f32x4 v[3];
    float ss = 0.f;
#pragma unroll
    for (int i = 0; i < 3; i++) {
        v[i] = ((const f32x4*)src)[lane + 64 * i];
        ss += v[i][0]*v[i][0] + v[i][1]*v[i][1] + v[i][2]*v[i][2] + v[i][3]*v[i][3];
    }
#pragma unroll
    for (int d = 1; d < 64; d <<= 1) ss += __shfl_xor(ss, d);
    float sc = 1.0f / (sqrtf(ss) + 1e-12f);
#pragma unroll
    for (int i = 0; i < 3; i++) {
        ushort4 o;
        o.x = f2bf(v[i][0] * sc); o.y = f2bf(v[i][1] * sc);
        o.z = f2bf(v[i][2] * sc); o.w = f2bf(v[i][3] * sc);
        ((ushort4*)dst)[lane + 64 * i] = o;
    }
}

// ---- kernel 2a (FAST): normalize bank -> bf16 Bn[NBPAD][DIM]; zero pad rows ----
__global__ void k_bn(const float* __restrict__ mb, unsigned short* __restrict__ Bn) {
    int wv = threadIdx.x >> 6, lane = threadIdx.x & 63;
    int r = blockIdx.x * 4 + wv;
    if (r >= NBPAD) return;
    unsigned short* dst = Bn + (size_t)r * DIM;
    if (r >= NBANK) {
        for (int i = lane; i < DIM / 4; i += 64)
            ((ushort4*)dst)[i] = make_ushort4(0, 0, 0, 0);
        return;
    }
    const f32x4* src = (const f32x4*)(mb + (size_t)r * DIM);
    f32x4 v[3];
    float ss = 0.f;
#pragma unroll
    for (int i = 0; i < 3; i++) {
        v[i] = src[lane + 64 * i];
        ss += v[i][0]*v[i][0] + v[i][1]*v[i][1] + v[i][2]*v[i][2] + v[i][3]*v[i][3];
    }
#pragma unroll
    for (int d = 1; d < 64; d <<= 1) ss += __shfl_xor(ss, d);
    float sc = 1.0f / (sqrtf(ss) + 1e-12f);
#pragma unroll
    for (int i = 0; i < 3; i++) {
        ushort4 o;
        o.x = f2bf(v[i][0] * sc); o.y = f2bf(v[i][1] * sc);
        o.z = f2bf(v[i][2] * sc); o.w = f2bf(v[i][3] * sc);
        ((ushort4*)dst)[lane + 64 * i] = o;
    }
}

// ---- kernel 2b (fallback): per-row 1/(||mb||+eps) ----
__global__ void k_rs(const float* __restrict__ mb, float* __restrict__ rs) {
    int wv = threadIdx.x >> 6, lane = threadIdx.x & 63;
    int r = blockIdx.x * 4 + wv;
    if (r >= NBANK) return;
    const f32x4* src = (const f32x4*)(mb + (size_t)r * DIM);
    float ss = 0.f;
#pragma unroll
    for (int i = 0; i < 3; i++) {
        f32x4 v = src[lane + 64 * i];
        ss += v[0]*v[0] + v[1]*v[1] + v[2]*v[2] + v[3]*v[3];
    }
#pragma unroll
    for (int d = 1; d < 64; d <<= 1) ss += __shfl_xor(ss, d);
    if (lane == 0) rs[r] = 1.0f / (sqrtf(ss) + 1e-12f);
}

// ---- kernel 3: bf16 MFMA GEMM, fused row-max -> atomicMax(keys) ----
// T2 swizzle: LDS tile is [row][8 chunks of 16B]; slot c holds global chunk c^(row&7).
// global_load_lds dest stays LINEAR (rule #21); the SOURCE chunk is permuted.
template<bool PREB>
__global__ void __launch_bounds__(256) k_gemm(const unsigned short* __restrict__ A,
                                              const unsigned short* __restrict__ Bn,
                                              const float* __restrict__ mb,
                                              const float* __restrict__ rs,
                                              unsigned* __restrict__ keys) {
    __shared__ unsigned short Al[2][BM * BK];   // 16 KB each
    __shared__ unsigned short Bl[2][BN * BK];

    // T1: bijective XCD swizzle (m204; nwg=19550, nwg%8=6)
    const int nwg = MT * NT;
    const int q = nwg >> 3, r8 = nwg & 7;
    const int xcd = blockIdx.x & 7, loc = blockIdx.x >> 3;
    const int wg = (xcd < r8 ? xcd * (q + 1) : r8 * (q + 1) + (xcd - r8) * q) + loc;
    const int mt = wg % MT;          // m-fastest within an XCD: 25 blocks share one B tile
    const int nt = wg / MT;

    const int t = threadIdx.x;
    const int lane = t & 63, wv = t >> 6;

    const unsigned short* Ab = A + (size_t)(mt * BM) * DIM;

    auto stage = [&](unsigned short (*L)[BM * BK], const unsigned short* gb, int buf, int kt) {
#pragma unroll
        for (int it = 0; it < 4; it++) {
            int id = it * 256 + t;
            int row = id >> 3, cs = id & 7;                       // linear LDS slot
            const unsigned short* g = gb + (size_t)row * DIM + kt * BK + ((cs ^ (row & 7)) << 3);
            unsigned short* l = &L[buf][id * 8];
            __builtin_amdgcn_global_load_lds(
                (const __attribute__((address_space(1))) unsigned int*)g,
                (__attribute__((address_space(3))) unsigned int*)l, 16, 0, 0);
        }
    };

    // fallback-path state (DCE'd when PREB)
    int brow[8];
    float rsv[8];
    f32x4 breg[8];
    if constexpr (!PREB) {
#pragma unroll
        for (int it = 0; it < 8; it++) {
            int id = it * 256 + t;
            int row = id >> 4;
            int gr = nt * BN + row;
            brow[it] = (gr < NBANK) ? gr : (NBANK - 1);
            rsv[it] = rs[brow[it]];
        }
    }
    auto loadB = [&](int kt) {
#pragma unroll
        for (int it = 0; it < 8; it++) {
            int id = it * 256 + t;
            int c4 = id & 15;
            breg[it] = *(const f32x4*)(mb + (size_t)brow[it] * DIM + kt * BK + c4 * 4);
        }
    };
    auto writeB = [&](int buf) {
#pragma unroll
        for (int it = 0; it < 8; it++) {
            int id = it * 256 + t;
            int row = id >> 4, c4 = id & 15;
            f32x4 v = breg[it] * rsv[it];
            ushort4 o;
            o.x = f2bf(v[0]); o.y = f2bf(v[1]); o.z = f2bf(v[2]); o.w = f2bf(v[3]);
            // swizzled write: 16B chunk (c4>>1) -> ^(row&7), 8B half = c4&1
            *(ushort4*)(&Bl[buf][row * BK + (((c4 >> 1) ^ (row & 7)) << 3) + (c4 & 1) * 4]) = o;
        }
    };

    // wave -> 64x64 quadrant; 4x4 fragments of 16x16x32
    f32x4 acc[4][4] = {};
    const int wm = (wv >> 1) * 64;
    const int wn = (wv & 1) * 64;
    const int lr = lane & 15;
    const int khi = lane >> 4;         // 0..3

    auto compute = [&](int buf) {
#pragma unroll
        for (int ks = 0; ks < BK; ks += 32) {
            int kc = (ks >> 3) + khi;  // 16B chunk index 0..7
            bf16x8 av[4], bv[4];
#pragma unroll
            for (int mi = 0; mi < 4; mi++) {
                int row = wm + mi * 16 + lr;
                av[mi] = __builtin_bit_cast(bf16x8,
                    *(const u32x4*)(&Al[buf][row * BK + ((kc ^ (row & 7)) << 3)]));
            }
#pragma unroll
            for (int ni = 0; ni < 4; ni++) {
                int row = wn + ni * 16 + lr;
                bv[ni] = __builtin_bit_cast(bf16x8,
                    *(const u32x4*)(&Bl[buf][row * BK + ((kc ^ (row & 7)) << 3)]));
            }
#pragma unroll
            for (int mi = 0; mi < 4; mi++)
#pragma unroll
                for (int ni = 0; ni < 4; ni++)
                    acc[mi][ni] = __builtin_amdgcn_mfma_f32_16x16x32_bf16(
                        av[mi], bv[ni], acc[mi][ni], 0, 0, 0);
        }
    };

    if constexpr (PREB) {
        const unsigned short* Bb = Bn + (size_t)(nt * BN) * DIM;
        stage(Al, Ab, 0, 0);
        stage(Bl, Bb, 0, 0);
        int cur = 0;
        for (int kt = 0; kt < KTILES; kt++) {
            __syncthreads();           // vmcnt drain -> buf cur staged
            if (kt + 1 < KTILES) { stage(Al, Ab, cur ^ 1, kt + 1); stage(Bl, Bb, cur ^ 1, kt + 1); }
            compute(cur);
            cur ^= 1;
        }
    } else {
        stage(Al, Ab, 0, 0);
        loadB(0);
        int cur = 0;
        for (int kt = 0; kt < KTILES; kt++) {
            writeB(cur);
            __syncthreads();
            if (kt + 1 < KTILES) { stage(Al, Ab, cur ^ 1, kt + 1); loadB(kt + 1); }
            compute(cur);
            cur ^= 1;
        }
    }

    // epilogue: row-max over this block's 128 columns, then global atomicMax
    const int rowbase = mt * BM + wm;
    const int colbase = nt * BN + wn;
#pragma unroll
    for (int mi = 0; mi < 4; mi++) {
#pragma unroll
        for (int j = 0; j < 4; j++) {
            float m = -3.4e38f;
#pragma unroll
            for (int ni = 0; ni < 4; ni++) {
                int col = colbase + ni * 16 + lr;
                if (col < NBANK) m = fmaxf(m, acc[mi][ni][j]);
            }
#pragma unroll
            for (int d = 1; d < 16; d <<= 1)
                m = fmaxf(m, __shfl_xor(m, d));
            if (lr == 0) {
                int row = rowbase + mi * 16 + khi * 4 + j;
                if (row < NPATCH) atomicMax(&keys[row], fkey(m));
            }
        }
    }
}

// ---- kernel 4: scores[b] = max_j sqrt(max(2 - 2*c_max, 1e-12)) ----
__global__ void k_final(const unsigned* __restrict__ keys, float* __restrict__ out) {
    int b = threadIdx.x;
    if (b >= 64) return;
    float best = 0.f;
    for (int j = 0; j < 49; j++) {
        float c = funkey(keys[b * 49 + j]);
        float d2 = fmaxf(2.0f - 2.0f * c, 1e-12f);
        best = fmaxf(best, sqrtf(d2));
    }
    out[b] = best;
}

extern "C" void kernel_launch(void* const* d_in, const int* in_sizes, int n_in,
                              void* d_out, int out_size, void* d_ws, size_t ws_size,
                              hipStream_t stream) {
    const float* tokens = (const float*)d_in[0];   // [64, 50, 768] f32
    const float* mb     = (const float*)d_in[1];   // [100000, 768] f32
    float* out = (float*)d_out;                    // [64] f32

    // ws layout: A bf16 [MPAD*DIM] | keys u32 [MPAD] | (Bn bf16 [NBPAD*DIM] | or rs f32 [NBANK])
    char* ws = (char*)d_ws;
    unsigned short* A = (unsigned short*)ws;
    unsigned* keys    = (unsigned*)(ws + (size_t)MPAD * DIM * 2);
    char* rest        = ws + (size_t)MPAD * DIM * 2 + (size_t)MPAD * 4;
    const size_t needFast = (size_t)MPAD * DIM * 2 + (size_t)MPAD * 4 + (size_t)NBPAD * DIM * 2;

    k_init   <<<(MPAD + 255) / 256, 256, 0, stream>>>(keys);
    k_patches<<<MPAD / 4, 256, 0, stream>>>(tokens, A);

    if (ws_size >= needFast) {
        unsigned short* Bnp = (unsigned short*)rest;
        k_bn  <<<NBPAD / 4, 256, 0, stream>>>(mb, Bnp);
        k_gemm<true><<<MT * NT, 256, 0, stream>>>(A, Bnp, nullptr, nullptr, keys);
    } else {
        float* rs = (float*)rest;
        k_rs  <<<(NBANK + 3) / 4, 256, 0, stream>>>(mb, rs);
        k_gemm<false><<<MT * NT, 256, 0, stream>>>(A, nullptr, mb, rs, keys);
    }
    k_final<<<1, 64, 0, stream>>>(keys, out);
}

// Round 3
// 447.723 us; speedup vs baseline: 4.3574x; 2.0507x over previous
//
#include <hip/hip_runtime.h>
#include <stdint.h>

// ---- problem constants ----
#define NPATCH 3136      // 64 images * 49 patches
#define MPAD   3200      // padded to 25 * 128
#define NBANK  100000
#define NBPAD  100096    // 782 * 128
#define DIM    768
#define BM 128
#define BN 128
#define BK 128              // int8 K-tile
#define KTILES (DIM / BK)   // 6
#define MT 25               // MPAD / BM
#define NT 782              // NBPAD / BN

typedef __attribute__((ext_vector_type(4))) float f32x4;
typedef __attribute__((ext_vector_type(4))) int   i32x4;

// monotonic float<->uint mapping for atomicMax on floats (incl. negatives)
__device__ __forceinline__ unsigned fkey(float f) {
    unsigned u = __float_as_uint(f);
    return (u & 0x80000000u) ? ~u : (u | 0x80000000u);
}
__device__ __forceinline__ float funkey(unsigned u) {
    return __uint_as_float((u & 0x80000000u) ? (u ^ 0x80000000u) : ~u);
}

// ---- kernel 0: zero the per-patch max-key buffer ----
__global__ void k_init(unsigned* __restrict__ keys) {
    int i = blockIdx.x * 256 + threadIdx.x;
    if (i < MPAD) keys[i] = 0u;
}

// ---- shared: quantize one 768-float row to int8 with scale sa = vmax/(127*(||a||+eps))
// q = round(127*a/vmax)  =>  sa*q ~= a/(||a||+eps)
__device__ __forceinline__ void quant_row(const float* __restrict__ src,
                                          signed char* __restrict__ dst,
                                          float* __restrict__ sa_p, int lane) {
    f32x4 v[3];
    float ss = 0.f, vm = 0.f;
#pragma unroll
    for (int i = 0; i < 3; i++) {
        v[i] = ((const f32x4*)src)[lane + 64 * i];
#pragma unroll
        for (int c = 0; c < 4; c++) {
            ss += v[i][c] * v[i][c];
            vm = fmaxf(vm, fabsf(v[i][c]));
        }
    }
#pragma unroll
    for (int d = 1; d < 64; d <<= 1) {
        ss += __shfl_xor(ss, d);
        vm = fmaxf(vm, __shfl_xor(vm, d));
    }
    float k = (vm > 0.f) ? 127.0f / vm : 0.f;
#pragma unroll
    for (int i = 0; i < 3; i++) {
        char4 o;
        o.x = (signed char)__float2int_rn(v[i][0] * k);
        o.y = (signed char)__float2int_rn(v[i][1] * k);
        o.z = (signed char)__float2int_rn(v[i][2] * k);
        o.w = (signed char)__float2int_rn(v[i][3] * k);
        ((char4*)dst)[lane + 64 * i] = o;
    }
    if (lane == 0) *sa_p = vm / (127.0f * (sqrtf(ss) + 1e-12f));
}

__device__ __forceinline__ void zero_row(signed char* __restrict__ dst,
                                         float* __restrict__ sa_p, int lane) {
    char4 z; z.x = z.y = z.z = z.w = 0;
#pragma unroll
    for (int i = 0; i < 3; i++) ((char4*)dst)[lane + 64 * i] = z;
    if (lane == 0) *sa_p = 0.f;
}

// ---- kernel 1: patches (drop CLS) -> int8 A[MPAD][DIM] + sa[MPAD] ----
__global__ void k_q8a(const float* __restrict__ tokens, signed char* __restrict__ A,
                      float* __restrict__ sa) {
    int wv = threadIdx.x >> 6, lane = threadIdx.x & 63;
    int r = blockIdx.x * 4 + wv;
    if (r >= MPAD) return;
    signed char* dst = A + (size_t)r * DIM;
    if (r >= NPATCH) { zero_row(dst, sa + r, lane); return; }
    int b = r / 49, j = r % 49;
    const float* src = tokens + (size_t)(b * 50 + 1 + j) * DIM;  // skip CLS
    quant_row(src, dst, sa + r, lane);
}

// ---- kernel 2: bank -> int8 Bq[NBPAD][DIM] + sb[NBPAD] ----
__global__ void k_q8b(const float* __restrict__ mb, signed char* __restrict__ Bq,
                      float* __restrict__ sb) {
    int wv = threadIdx.x >> 6, lane = threadIdx.x & 63;
    int r = blockIdx.x * 4 + wv;
    if (r >= NBPAD) return;
    signed char* dst = Bq + (size_t)r * DIM;
    if (r >= NBANK) { zero_row(dst, sb + r, lane); return; }
    quant_row(mb + (size_t)r * DIM, dst, sb + r, lane);
}

// ---- kernel 3: int8 MFMA GEMM, fused row-max -> atomicMax(keys) ----
// LDS tile rows are 128 B = 8 chunks of 16 B; slot c holds global chunk c^(row&7).
// global_load_lds dest stays LINEAR (rule #21); the SOURCE chunk is permuted.
__global__ void __launch_bounds__(256) k_gemm(const signed char* __restrict__ A,
                                              const signed char* __restrict__ Bq,
                                              const float* __restrict__ sb,
                                              unsigned* __restrict__ keys) {
    __shared__ signed char Al[2][BM * BK];   // 16 KB each buf
    __shared__ signed char Bl[2][BN * BK];

    // T1: bijective XCD swizzle (m204; nwg=19550, nwg%8=6)
    const int nwg = MT * NT;
    const int q = nwg >> 3, r8 = nwg & 7;
    const int xcd = blockIdx.x & 7, loc = blockIdx.x >> 3;
    const int wg = (xcd < r8 ? xcd * (q + 1) : r8 * (q + 1) + (xcd - r8) * q) + loc;
    const int mt = wg % MT;          // m-fastest within an XCD: 25 blocks share one B tile
    const int nt = wg / MT;

    const int t = threadIdx.x;
    const int lane = t & 63, wv = t >> 6;

    const signed char* Ab = A + (size_t)(mt * BM) * DIM;
    const signed char* Bb = Bq + (size_t)(nt * BN) * DIM;

    auto stage = [&](signed char (*L)[BM * BK], const signed char* gb, int buf, int kt) {
#pragma unroll
        for (int it = 0; it < 4; it++) {
            int id = it * 256 + t;
            int row = id >> 3, cs = id & 7;                       // linear LDS slot
            const signed char* g = gb + (size_t)row * DIM + kt * BK + ((cs ^ (row & 7)) << 4);
            signed char* l = &L[buf][id * 16];
            __builtin_amdgcn_global_load_lds(
                (const __attribute__((address_space(1))) unsigned int*)g,
                (__attribute__((address_space(3))) unsigned int*)l, 16, 0, 0);
        }
    };

    // wave -> 64x64 quadrant; 4x4 fragments of 16x16x64 (i8)
    i32x4 acc[4][4] = {};
    const int wm = (wv >> 1) * 64;
    const int wn = (wv & 1) * 64;
    const int lr = lane & 15;
    const int khi = lane >> 4;         // 0..3 -> k-base khi*16 elements

    auto compute = [&](int buf) {
#pragma unroll
        for (int ks = 0; ks < BK; ks += 64) {
            int kc = (ks >> 4) + khi;  // 16B chunk index 0..7
            i32x4 av[4], bv[4];
#pragma unroll
            for (int mi = 0; mi < 4; mi++) {
                int row = wm + mi * 16 + lr;
                av[mi] = *(const i32x4*)(&Al[buf][row * BK + ((kc ^ (row & 7)) << 4)]);
            }
#pragma unroll
            for (int ni = 0; ni < 4; ni++) {
                int row = wn + ni * 16 + lr;
                bv[ni] = *(const i32x4*)(&Bl[buf][row * BK + ((kc ^ (row & 7)) << 4)]);
            }
#pragma unroll
            for (int mi = 0; mi < 4; mi++)
#pragma unroll
                for (int ni = 0; ni < 4; ni++)
                    acc[mi][ni] = __builtin_amdgcn_mfma_i32_16x16x64_i8(
                        av[mi], bv[ni], acc[mi][ni], 0, 0, 0);
        }
    };

    stage(Al, Ab, 0, 0);
    stage(Bl, Bb, 0, 0);
    int cur = 0;
    for (int kt = 0; kt < KTILES; kt++) {
        __syncthreads();               // drains vmcnt -> buf cur staged; prev reads done
        if (kt + 1 < KTILES) { stage(Al, Ab, cur ^ 1, kt + 1); stage(Bl, Bb, cur ^ 1, kt + 1); }
        compute(cur);
        cur ^= 1;
    }

    // epilogue: m = max over this block's 128 cols of sb[col]*dot; atomicMax per row.
    // sa[row] is a positive per-row constant -> applied in k_final (max commutes).
    const int rowbase = mt * BM + wm;
    const int colbase = nt * BN + wn;
    float sbv[4];
#pragma unroll
    for (int ni = 0; ni < 4; ni++) sbv[ni] = sb[colbase + ni * 16 + lr];
#pragma unroll
    for (int mi = 0; mi < 4; mi++) {
#pragma unroll
        for (int j = 0; j < 4; j++) {
            float m = -3.4e38f;
#pragma unroll
            for (int ni = 0; ni < 4; ni++) {
                int col = colbase + ni * 16 + lr;
                if (col < NBANK) m = fmaxf(m, sbv[ni] * (float)acc[mi][ni][j]);
            }
#pragma unroll
            for (int d = 1; d < 16; d <<= 1)   // reduce 16 lanes sharing a C-row
                m = fmaxf(m, __shfl_xor(m, d));
            if (lr == 0) {
                int row = rowbase + mi * 16 + khi * 4 + j;
                if (row < NPATCH) atomicMax(&keys[row], fkey(m));
            }
        }
    }
}

// ---- kernel 4: scores[b] = max_j sqrt(max(2 - 2*sa*keymax, 1e-12)) ----
__global__ void k_final(const unsigned* __restrict__ keys, const float* __restrict__ sa,
                        float* __restrict__ out) {
    int b = threadIdx.x;
    if (b >= 64) return;
    float best = 0.f;
    for (int j = 0; j < 49; j++) {
        int row = b * 49 + j;
        float c = sa[row] * funkey(keys[row]);
        float d2 = fmaxf(2.0f - 2.0f * c, 1e-12f);
        best = fmaxf(best, sqrtf(d2));
    }
    out[b] = best;
}

extern "C" void kernel_launch(void* const* d_in, const int* in_sizes, int n_in,
                              void* d_out, int out_size, void* d_ws, size_t ws_size,
                              hipStream_t stream) {
    const float* tokens = (const float*)d_in[0];   // [64, 50, 768] f32
    const float* mb     = (const float*)d_in[1];   // [100000, 768] f32
    float* out = (float*)d_out;                    // [64] f32

    // ws layout (16B-aligned regions):
    //   Aq i8 [MPAD*DIM] | Bq i8 [NBPAD*DIM] | sa f32[MPAD] | sb f32[NBPAD] | keys u32[MPAD]
    char* ws = (char*)d_ws;
    signed char* Aq = (signed char*)ws;
    signed char* Bq = (signed char*)(ws + (size_t)MPAD * DIM);
    float* sa       = (float*)(ws + (size_t)MPAD * DIM + (size_t)NBPAD * DIM);
    float* sb       = sa + MPAD;
    unsigned* keys  = (unsigned*)(sb + NBPAD);

    k_init <<<(MPAD + 255) / 256, 256, 0, stream>>>(keys);
    k_q8a  <<<MPAD / 4, 256, 0, stream>>>(tokens, Aq, sa);
    k_q8b  <<<NBPAD / 4, 256, 0, stream>>>(mb, Bq, sb);
    k_gemm <<<MT * NT, 256, 0, stream>>>(Aq, Bq, sb, keys);
    k_final<<<1, 64, 0, stream>>>(keys, sa, out);
}

// Round 4
// 441.624 us; speedup vs baseline: 4.4175x; 1.0138x over previous
//
#include <hip/hip_runtime.h>
#include <stdint.h>

// ---- problem constants ----
#define NPATCH 3136      // 64 images * 49 patches
#define MPAD   3328      // padded to 13 * 256
#define NBANK  100000
#define NBPAD  100096    // 782 * 128
#define DIM    768
#define BM 256
#define BN 128
#define BK 128              // int8 K-tile (128 B rows)
#define KTILES (DIM / BK)   // 6
#define MT 13               // MPAD / BM
#define NT 782              // NBPAD / BN
#define ABYTES (BM * BK)    // 32 KB
#define BBYTES (BN * BK)    // 16 KB

typedef __attribute__((ext_vector_type(4))) float f32x4;
typedef __attribute__((ext_vector_type(4))) int   i32x4;

// monotonic float<->uint mapping for atomicMax on floats (incl. negatives)
__device__ __forceinline__ unsigned fkey(float f) {
    unsigned u = __float_as_uint(f);
    return (u & 0x80000000u) ? ~u : (u | 0x80000000u);
}
__device__ __forceinline__ float funkey(unsigned u) {
    return __uint_as_float((u & 0x80000000u) ? (u ^ 0x80000000u) : ~u);
}

// ---- kernel 0: zero the per-patch max-key buffer ----
__global__ void k_init(unsigned* __restrict__ keys) {
    int i = blockIdx.x * 256 + threadIdx.x;
    if (i < MPAD) keys[i] = 0u;
}

// ---- shared: quantize one 768-float row to int8 with scale sa = vmax/(127*(||a||+eps))
__device__ __forceinline__ void quant_row(const float* __restrict__ src,
                                          signed char* __restrict__ dst,
                                          float* __restrict__ sa_p, int lane) {
    f32x4 v[3];
    float ss = 0.f, vm = 0.f;
#pragma unroll
    for (int i = 0; i < 3; i++) {
        v[i] = ((const f32x4*)src)[lane + 64 * i];
#pragma unroll
        for (int c = 0; c < 4; c++) {
            ss += v[i][c] * v[i][c];
            vm = fmaxf(vm, fabsf(v[i][c]));
        }
    }
#pragma unroll
    for (int d = 1; d < 64; d <<= 1) {
        ss += __shfl_xor(ss, d);
        vm = fmaxf(vm, __shfl_xor(vm, d));
    }
    float k = (vm > 0.f) ? 127.0f / vm : 0.f;
#pragma unroll
    for (int i = 0; i < 3; i++) {
        char4 o;
        o.x = (signed char)__float2int_rn(v[i][0] * k);
        o.y = (signed char)__float2int_rn(v[i][1] * k);
        o.z = (signed char)__float2int_rn(v[i][2] * k);
        o.w = (signed char)__float2int_rn(v[i][3] * k);
        ((char4*)dst)[lane + 64 * i] = o;
    }
    if (lane == 0) *sa_p = vm / (127.0f * (sqrtf(ss) + 1e-12f));
}

__device__ __forceinline__ void zero_row(signed char* __restrict__ dst,
                                         float* __restrict__ sa_p, int lane) {
    char4 z; z.x = z.y = z.z = z.w = 0;
#pragma unroll
    for (int i = 0; i < 3; i++) ((char4*)dst)[lane + 64 * i] = z;
    if (lane == 0) *sa_p = 0.f;
}

// ---- kernel 1: patches (drop CLS) -> int8 A[MPAD][DIM] + sa[MPAD] ----
__global__ void k_q8a(const float* __restrict__ tokens, signed char* __restrict__ A,
                      float* __restrict__ sa) {
    int wv = threadIdx.x >> 6, lane = threadIdx.x & 63;
    int r = blockIdx.x * 4 + wv;
    if (r >= MPAD) return;
    signed char* dst = A + (size_t)r * DIM;
    if (r >= NPATCH) { zero_row(dst, sa + r, lane); return; }
    int b = r / 49, j = r % 49;
    const float* src = tokens + (size_t)(b * 50 + 1 + j) * DIM;  // skip CLS
    quant_row(src, dst, sa + r, lane);
}

// ---- kernel 2: bank -> int8 Bq[NBPAD][DIM] + sb[NBPAD] ----
__global__ void k_q8b(const float* __restrict__ mb, signed char* __restrict__ Bq,
                      float* __restrict__ sb) {
    int wv = threadIdx.x >> 6, lane = threadIdx.x & 63;
    int r = blockIdx.x * 4 + wv;
    if (r >= NBPAD) return;
    signed char* dst = Bq + (size_t)r * DIM;
    if (r >= NBANK) { zero_row(dst, sb + r, lane); return; }
    quant_row(mb + (size_t)r * DIM, dst, sb + r, lane);
}

// ---- kernel 3: int8 MFMA GEMM, 3-buffer rotating pipeline (depth-2 prefetch),
//      counted vmcnt (never 0 in steady state), raw barriers, setprio on MFMA.
// LDS rows are 128 B = 8 chunks of 16 B; slot c holds global chunk c^(row&7).
// global_load_lds dest stays LINEAR (rule #21); the SOURCE chunk is permuted.
__global__ void __launch_bounds__(512, 1) k_gemm(const signed char* __restrict__ A,
                                                 const signed char* __restrict__ Bq,
                                                 const float* __restrict__ sb,
                                                 unsigned* __restrict__ keys) {
    __shared__ __align__(16) signed char lds[3][ABYTES + BBYTES];   // 144 KB

    // T1: bijective XCD swizzle (m204; nwg=10166, nwg%8=6)
    const int nwg = MT * NT;
    const int q = nwg >> 3, r8 = nwg & 7;
    const int xcd = blockIdx.x & 7, loc = blockIdx.x >> 3;
    const int wg = (xcd < r8 ? xcd * (q + 1) : r8 * (q + 1) + (xcd - r8) * q) + loc;
    const int mt = wg % MT;          // m-fastest within an XCD: 13 blocks share one B tile
    const int nt = wg / MT;

    const int t = threadIdx.x;
    const int lane = t & 63, wv = t >> 6;

    const signed char* Ab = A + (size_t)(mt * BM) * DIM;
    const signed char* Bb = Bq + (size_t)(nt * BN) * DIM;

    // 6 global_load_lds per thread per K-tile (A:4, B:2)
    auto stageAB = [&](int buf, int kt) {
#pragma unroll
        for (int it = 0; it < 4; it++) {               // A: 2048 chunks of 16 B
            int id = it * 512 + t;
            int row = id >> 3, cs = id & 7;            // linear LDS slot
            const signed char* g = Ab + (size_t)row * DIM + kt * BK + ((cs ^ (row & 7)) << 4);
            __builtin_amdgcn_global_load_lds(
                (const __attribute__((address_space(1))) unsigned int*)g,
                (__attribute__((address_space(3))) unsigned int*)(&lds[buf][id * 16]), 16, 0, 0);
        }
#pragma unroll
        for (int it = 0; it < 2; it++) {               // B: 1024 chunks of 16 B
            int id = it * 512 + t;
            int row = id >> 3, cs = id & 7;
            const signed char* g = Bb + (size_t)row * DIM + kt * BK + ((cs ^ (row & 7)) << 4);
            __builtin_amdgcn_global_load_lds(
                (const __attribute__((address_space(1))) unsigned int*)g,
                (__attribute__((address_space(3))) unsigned int*)(&lds[buf][ABYTES + id * 16]), 16, 0, 0);
        }
    };

    // wave -> 64x64 quadrant (4M x 2N wave grid); 4x4 fragments of 16x16x64 i8
    i32x4 acc[4][4] = {};
    const int wm = (wv >> 1) * 64;
    const int wn = (wv & 1) * 64;
    const int lr = lane & 15;
    const int khi = lane >> 4;         // 0..3 -> 16B k-chunk within 64-elem k-step

    auto compute = [&](int buf) {
        const signed char* Abuf = &lds[buf][0];
        const signed char* Bbuf = &lds[buf][ABYTES];
#pragma unroll
        for (int ks = 0; ks < 2; ks++) {
            int kc = ks * 4 + khi;     // 16B chunk index 0..7
            i32x4 av[4], bv[4];
#pragma unroll
            for (int mi = 0; mi < 4; mi++) {
                int row = wm + mi * 16 + lr;
                av[mi] = *(const i32x4*)(Abuf + row * BK + ((kc ^ (row & 7)) << 4));
            }
#pragma unroll
            for (int ni = 0; ni < 4; ni++) {
                int row = wn + ni * 16 + lr;
                bv[ni] = *(const i32x4*)(Bbuf + row * BK + ((kc ^ (row & 7)) << 4));
            }
            __builtin_amdgcn_s_setprio(1);
#pragma unroll
            for (int mi = 0; mi < 4; mi++)
#pragma unroll
                for (int ni = 0; ni < 4; ni++)
                    acc[mi][ni] = __builtin_amdgcn_mfma_i32_16x16x64_i8(
                        av[mi], bv[ni], acc[mi][ni], 0, 0, 0);
            __builtin_amdgcn_s_setprio(0);
        }
    };

    // prologue: tiles 0,1 in flight
    stageAB(0, 0);
    stageAB(1, 1);
#pragma unroll
    for (int tt = 0; tt < KTILES; tt++) {
        // tile tt landed (6 loads); tile tt+1's 6 may stay in flight
        if (tt < KTILES - 1) asm volatile("s_waitcnt vmcnt(6)" ::: "memory");
        else                 asm volatile("s_waitcnt vmcnt(0)" ::: "memory");
        __builtin_amdgcn_s_barrier();      // all waves done reading buf (tt-1)%3
        __builtin_amdgcn_sched_barrier(0);
        if (tt + 2 < KTILES) stageAB((tt + 2) % 3, tt + 2);   // into the freed buffer
        compute(tt % 3);
    }

    // epilogue: m = max over this block's cols of sb[col]*dot; atomicMax per row.
    // sa[row] is a positive per-row constant -> applied in k_final (max commutes).
    const int rowbase = mt * BM + wm;
    const int colbase = nt * BN + wn;
    float sbv[4];
#pragma unroll
    for (int ni = 0; ni < 4; ni++) sbv[ni] = sb[colbase + ni * 16 + lr];
#pragma unroll
    for (int mi = 0; mi < 4; mi++) {
#pragma unroll
        for (int j = 0; j < 4; j++) {
            float m = -3.4e38f;
#pragma unroll
            for (int ni = 0; ni < 4; ni++) {
                int col = colbase + ni * 16 + lr;
                if (col < NBANK) m = fmaxf(m, sbv[ni] * (float)acc[mi][ni][j]);
            }
#pragma unroll
            for (int d = 1; d < 16; d <<= 1)   // reduce 16 lanes sharing a C-row
                m = fmaxf(m, __shfl_xor(m, d));
            if (lr == 0) {
                int row = rowbase + mi * 16 + khi * 4 + j;
                if (row < NPATCH) atomicMax(&keys[row], fkey(m));
            }
        }
    }
}

// ---- kernel 4: scores[b] = max_j sqrt(max(2 - 2*sa*keymax, 1e-12)) ----
__global__ void k_final(const unsigned* __restrict__ keys, const float* __restrict__ sa,
                        float* __restrict__ out) {
    int b = threadIdx.x;
    if (b >= 64) return;
    float best = 0.f;
    for (int j = 0; j < 49; j++) {
        int row = b * 49 + j;
        float c = sa[row] * funkey(keys[row]);
        float d2 = fmaxf(2.0f - 2.0f * c, 1e-12f);
        best = fmaxf(best, sqrtf(d2));
    }
    out[b] = best;
}

extern "C" void kernel_launch(void* const* d_in, const int* in_sizes, int n_in,
                              void* d_out, int out_size, void* d_ws, size_t ws_size,
                              hipStream_t stream) {
    const float* tokens = (const float*)d_in[0];   // [64, 50, 768] f32
    const float* mb     = (const float*)d_in[1];   // [100000, 768] f32
    float* out = (float*)d_out;                    // [64] f32

    // ws layout (16B-aligned regions):
    //   Aq i8 [MPAD*DIM] | Bq i8 [NBPAD*DIM] | sa f32[MPAD] | sb f32[NBPAD] | keys u32[MPAD]
    char* ws = (char*)d_ws;
    signed char* Aq = (signed char*)ws;
    signed char* Bq = (signed char*)(ws + (size_t)MPAD * DIM);
    float* sa       = (float*)(ws + (size_t)MPAD * DIM + (size_t)NBPAD * DIM);
    float* sb       = sa + MPAD;
    unsigned* keys  = (unsigned*)(sb + NBPAD);

    k_init <<<(MPAD + 255) / 256, 256, 0, stream>>>(keys);
    k_q8a  <<<MPAD / 4, 256, 0, stream>>>(tokens, Aq, sa);
    k_q8b  <<<NBPAD / 4, 256, 0, stream>>>(mb, Bq, sb);
    k_gemm <<<MT * NT, 512, 0, stream>>>(Aq, Bq, sb, keys);
    k_final<<<1, 64, 0, stream>>>(keys, sa, out);
}

// Round 5
// 402.196 us; speedup vs baseline: 4.8506x; 1.0980x over previous
//
#include <hip/hip_runtime.h>
#include <stdint.h>

// ---- problem constants ----
#define NPATCH 3136      // 64 images * 49 patches
#define MPAD   3328      // 13 * 256
#define NBANK  100000
#define NBPAD  100096    // 391 * 256
#define DIM    768
#define BM 256
#define BN 256
#define BK 128              // int8 K-tile (128 B rows)
#define KTILES (DIM / BK)   // 6
#define MT 13               // MPAD / BM
#define NT 391              // NBPAD / BN
#define ABYTES (BM * BK)    // 32 KB
#define BBYTES (BN * BK)    // 32 KB

typedef __attribute__((ext_vector_type(4))) float f32x4;
typedef __attribute__((ext_vector_type(4))) int   i32x4;

// monotonic float<->uint mapping for atomicMax on floats (incl. negatives)
__device__ __forceinline__ unsigned fkey(float f) {
    unsigned u = __float_as_uint(f);
    return (u & 0x80000000u) ? ~u : (u | 0x80000000u);
}
__device__ __forceinline__ float funkey(unsigned u) {
    return __uint_as_float((u & 0x80000000u) ? (u ^ 0x80000000u) : ~u);
}

// ---- kernel 0: zero the per-patch max-key buffer ----
__global__ void k_init(unsigned* __restrict__ keys) {
    int i = blockIdx.x * 256 + threadIdx.x;
    if (i < MPAD) keys[i] = 0u;
}

// ---- shared: quantize one 768-float row to int8 with scale sa = vmax/(127*(||a||+eps))
__device__ __forceinline__ void quant_row(const float* __restrict__ src,
                                          signed char* __restrict__ dst,
                                          float* __restrict__ sa_p, int lane) {
    f32x4 v[3];
    float ss = 0.f, vm = 0.f;
#pragma unroll
    for (int i = 0; i < 3; i++) {
        v[i] = ((const f32x4*)src)[lane + 64 * i];
#pragma unroll
        for (int c = 0; c < 4; c++) {
            ss += v[i][c] * v[i][c];
            vm = fmaxf(vm, fabsf(v[i][c]));
        }
    }
#pragma unroll
    for (int d = 1; d < 64; d <<= 1) {
        ss += __shfl_xor(ss, d);
        vm = fmaxf(vm, __shfl_xor(vm, d));
    }
    float k = (vm > 0.f) ? 127.0f / vm : 0.f;
#pragma unroll
    for (int i = 0; i < 3; i++) {
        char4 o;
        o.x = (signed char)__float2int_rn(v[i][0] * k);
        o.y = (signed char)__float2int_rn(v[i][1] * k);
        o.z = (signed char)__float2int_rn(v[i][2] * k);
        o.w = (signed char)__float2int_rn(v[i][3] * k);
        ((char4*)dst)[lane + 64 * i] = o;
    }
    if (lane == 0) *sa_p = vm / (127.0f * (sqrtf(ss) + 1e-12f));
}

__device__ __forceinline__ void zero_row(signed char* __restrict__ dst,
                                         float* __restrict__ sa_p, int lane) {
    char4 z; z.x = z.y = z.z = z.w = 0;
#pragma unroll
    for (int i = 0; i < 3; i++) ((char4*)dst)[lane + 64 * i] = z;
    if (lane == 0) *sa_p = 0.f;
}

// ---- kernel 1: patches (drop CLS) -> int8 A[MPAD][DIM] + sa[MPAD] ----
__global__ void k_q8a(const float* __restrict__ tokens, signed char* __restrict__ A,
                      float* __restrict__ sa) {
    int wv = threadIdx.x >> 6, lane = threadIdx.x & 63;
    int r = blockIdx.x * 4 + wv;
    if (r >= MPAD) return;
    signed char* dst = A + (size_t)r * DIM;
    if (r >= NPATCH) { zero_row(dst, sa + r, lane); return; }
    int b = r / 49, j = r % 49;
    const float* src = tokens + (size_t)(b * 50 + 1 + j) * DIM;  // skip CLS
    quant_row(src, dst, sa + r, lane);
}

// ---- kernel 2: bank -> int8 Bq[NBPAD][DIM] + sb[NBPAD] ----
__global__ void k_q8b(const float* __restrict__ mb, signed char* __restrict__ Bq,
                      float* __restrict__ sb) {
    int wv = threadIdx.x >> 6, lane = threadIdx.x & 63;
    int r = blockIdx.x * 4 + wv;
    if (r >= NBPAD) return;
    signed char* dst = Bq + (size_t)r * DIM;
    if (r >= NBANK) { zero_row(dst, sb + r, lane); return; }
    quant_row(mb + (size_t)r * DIM, dst, sb + r, lane);
}

// ---- kernel 3: int8 MFMA GEMM, 256x256 tile, 8 waves of 128x64, 2-phase
//      double-buffer (T3-minimum recipe: STAGE(next); compute(cur); sync per tile).
// LDS rows are 128 B = 8 chunks of 16 B; slot c holds global chunk c^(row&7).
// global_load_lds dest stays LINEAR (rule #21); the SOURCE chunk is permuted.
__global__ void __launch_bounds__(512, 2) k_gemm(const signed char* __restrict__ A,
                                                 const signed char* __restrict__ Bq,
                                                 const float* __restrict__ sb,
                                                 unsigned* __restrict__ keys) {
    __shared__ __align__(16) signed char lds[2][ABYTES + BBYTES];   // 128 KB

    // T1: bijective XCD swizzle (m204; nwg=5083, nwg%8=3)
    const int nwg = MT * NT;
    const int q = nwg >> 3, r8 = nwg & 7;
    const int xcd = blockIdx.x & 7, loc = blockIdx.x >> 3;
    const int wg = (xcd < r8 ? xcd * (q + 1) : r8 * (q + 1) + (xcd - r8) * q) + loc;
    const int mt = wg % MT;          // m-fastest within an XCD: 13 blocks share one B tile
    const int nt = wg / MT;

    const int t = threadIdx.x;
    const int lane = t & 63, wv = t >> 6;

    const signed char* Ab = A + (size_t)(mt * BM) * DIM;
    const signed char* Bb = Bq + (size_t)(nt * BN) * DIM;

    // 8 global_load_lds per thread per K-tile (A:4, B:4); 2048 chunks each of A,B
    auto stageAB = [&](int buf, int kt) {
#pragma unroll
        for (int it = 0; it < 4; it++) {               // A
            int id = it * 512 + t;
            int row = id >> 3, cs = id & 7;            // linear LDS slot
            const signed char* g = Ab + (size_t)row * DIM + kt * BK + ((cs ^ (row & 7)) << 4);
            __builtin_amdgcn_global_load_lds(
                (const __attribute__((address_space(1))) unsigned int*)g,
                (__attribute__((address_space(3))) unsigned int*)(&lds[buf][id * 16]), 16, 0, 0);
        }
#pragma unroll
        for (int it = 0; it < 4; it++) {               // B
            int id = it * 512 + t;
            int row = id >> 3, cs = id & 7;
            const signed char* g = Bb + (size_t)row * DIM + kt * BK + ((cs ^ (row & 7)) << 4);
            __builtin_amdgcn_global_load_lds(
                (const __attribute__((address_space(1))) unsigned int*)g,
                (__attribute__((address_space(3))) unsigned int*)(&lds[buf][ABYTES + id * 16]), 16, 0, 0);
        }
    };

    // wave -> 128x64 output tile; wave grid 2M x 4N over 256x256
    i32x4 acc[8][4] = {};
    const int wm = (wv >> 2) * 128;    // 0 or 128
    const int wn = (wv & 3) * 64;      // 0,64,128,192
    const int lr = lane & 15;
    const int khi = lane >> 4;         // 0..3 -> 16B k-chunk within 64-elem k-step

    auto compute = [&](int buf) {
        const signed char* Abuf = &lds[buf][0];
        const signed char* Bbuf = &lds[buf][ABYTES];
#pragma unroll
        for (int ks = 0; ks < 2; ks++) {
            int kc = ks * 4 + khi;     // 16B chunk index 0..7
            i32x4 av[8], bv[4];
#pragma unroll
            for (int mi = 0; mi < 8; mi++) {
                int row = wm + mi * 16 + lr;
                av[mi] = *(const i32x4*)(Abuf + row * BK + ((kc ^ (row & 7)) << 4));
            }
#pragma unroll
            for (int ni = 0; ni < 4; ni++) {
                int row = wn + ni * 16 + lr;
                bv[ni] = *(const i32x4*)(Bbuf + row * BK + ((kc ^ (row & 7)) << 4));
            }
            __builtin_amdgcn_s_setprio(1);
#pragma unroll
            for (int mi = 0; mi < 8; mi++)
#pragma unroll
                for (int ni = 0; ni < 4; ni++)
                    acc[mi][ni] = __builtin_amdgcn_mfma_i32_16x16x64_i8(
                        av[mi], bv[ni], acc[mi][ni], 0, 0, 0);
            __builtin_amdgcn_s_setprio(0);
        }
    };

    // T3-minimum 2-phase: stage(next) issued BEFORE compute(cur); one
    // vmcnt(0)+barrier (= __syncthreads) per K-tile, after compute.
    stageAB(0, 0);
    __syncthreads();                    // tile 0 landed (all waves)
#pragma unroll
    for (int tt = 0; tt < KTILES; tt++) {
        if (tt + 1 < KTILES) stageAB((tt + 1) & 1, tt + 1);  // DMA flies during compute
        compute(tt & 1);
        if (tt + 1 < KTILES) __syncthreads();  // drains tile tt+1 DMA; frees buf tt&1
    }

    // epilogue: m = max over this block's cols of sb[col]*dot; atomicMax per row.
    // sa[row] is a positive per-row constant -> applied in k_final (max commutes).
    const int rowbase = mt * BM + wm;
    const int colbase = nt * BN + wn;
    float sbv[4];
#pragma unroll
    for (int ni = 0; ni < 4; ni++) sbv[ni] = sb[colbase + ni * 16 + lr];
#pragma unroll
    for (int mi = 0; mi < 8; mi++) {
#pragma unroll
        for (int j = 0; j < 4; j++) {
            float m = -3.4e38f;
#pragma unroll
            for (int ni = 0; ni < 4; ni++) {
                int col = colbase + ni * 16 + lr;
                if (col < NBANK) m = fmaxf(m, sbv[ni] * (float)acc[mi][ni][j]);
            }
#pragma unroll
            for (int d = 1; d < 16; d <<= 1)   // reduce 16 lanes sharing a C-row
                m = fmaxf(m, __shfl_xor(m, d));
            if (lr == 0) {
                int row = rowbase + mi * 16 + khi * 4 + j;
                if (row < NPATCH) atomicMax(&keys[row], fkey(m));
            }
        }
    }
}

// ---- kernel 4: scores[b] = max_j sqrt(max(2 - 2*sa*keymax, 1e-12)) ----
__global__ void k_final(const unsigned* __restrict__ keys, const float* __restrict__ sa,
                        float* __restrict__ out) {
    int b = threadIdx.x;
    if (b >= 64) return;
    float best = 0.f;
    for (int j = 0; j < 49; j++) {
        int row = b * 49 + j;
        float c = sa[row] * funkey(keys[row]);
        float d2 = fmaxf(2.0f - 2.0f * c, 1e-12f);
        best = fmaxf(best, sqrtf(d2));
    }
    out[b] = best;
}

extern "C" void kernel_launch(void* const* d_in, const int* in_sizes, int n_in,
                              void* d_out, int out_size, void* d_ws, size_t ws_size,
                              hipStream_t stream) {
    const float* tokens = (const float*)d_in[0];   // [64, 50, 768] f32
    const float* mb     = (const float*)d_in[1];   // [100000, 768] f32
    float* out = (float*)d_out;                    // [64] f32

    // ws layout (16B-aligned regions):
    //   Aq i8 [MPAD*DIM] | Bq i8 [NBPAD*DIM] | sa f32[MPAD] | sb f32[NBPAD] | keys u32[MPAD]
    char* ws = (char*)d_ws;
    signed char* Aq = (signed char*)ws;
    signed char* Bq = (signed char*)(ws + (size_t)MPAD * DIM);
    float* sa       = (float*)(ws + (size_t)MPAD * DIM + (size_t)NBPAD * DIM);
    float* sb       = sa + MPAD;
    unsigned* keys  = (unsigned*)(sb + NBPAD);

    k_init <<<(MPAD + 255) / 256, 256, 0, stream>>>(keys);
    k_q8a  <<<MPAD / 4, 256, 0, stream>>>(tokens, Aq, sa);
    k_q8b  <<<NBPAD / 4, 256, 0, stream>>>(mb, Bq, sb);
    k_gemm <<<MT * NT, 512, 0, stream>>>(Aq, Bq, sb, keys);
    k_final<<<1, 64, 0, stream>>>(keys, sa, out);
}